// Round 3
// baseline (857.388 us; speedup 1.0000x reference)
//
#include <hip/hip_runtime.h>

#define BSZ   4
#define WSEQ  768
#define LSEQ  8192
#define NFFT  8192   // packed complex FFT length (real length 16384)
#define MH    4096
#define EMB   33
#define ORDER 64

// workspace layout (float units)
#define KFROW   16448          // per-w row: holds k reals then 8193 complex (padded)
#define WS_TWN  0              // 2048 complex  e^{-2pi q/8192}
#define WS_TW2N 4096           // 8192 complex  e^{-2pi k/16384}
#define WS_H    20480          // h: 8192 x 64
#define WS_KF   544768         // 768 rows x KFROW floats  (~50 MB total ws)

__device__ __forceinline__ int swz(int a){ return a ^ (((a >> 5) & 7) << 2); }

// ---------------- twiddle tables (built in fp64 once per launch) ----------------
__global__ void tables_kernel(float* __restrict__ ws){
  int t = blockIdx.x * 256 + threadIdx.x;
  const double TWO_PI = 6.283185307179586476925286766559;
  if (t < 2048){
    double ang = -TWO_PI * (double)t / 8192.0;
    ws[WS_TWN + 2*t]   = (float)cos(ang);
    ws[WS_TWN + 2*t+1] = (float)sin(ang);
  }
  int k = t - 2048;
  if (k >= 0 && k < NFFT){
    double ang = -TWO_PI * (double)k / 16384.0;
    ws[WS_TW2N + 2*k]   = (float)cos(ang);
    ws[WS_TW2N + 2*k+1] = (float)sin(ang);
  }
}

// ---------------- implicit filter MLP: z[8192,33] -> h[8192,64] ----------------
__global__ void mlp_kernel(const float* __restrict__ z, const float* __restrict__ freq,
                           const float* __restrict__ w0, const float* __restrict__ b0,
                           const float* __restrict__ w1, const float* __restrict__ b1,
                           const float* __restrict__ w2, const float* __restrict__ b2,
                           float* __restrict__ ws){
  int l = blockIdx.x * 256 + threadIdx.x;
  if (l >= LSEQ) return;
  float zv[EMB];
  #pragma unroll
  for (int e = 0; e < EMB; ++e) zv[e] = z[l*EMB + e];
  float h1[ORDER];
  #pragma unroll 2
  for (int o = 0; o < ORDER; ++o){
    float a = b0[o];
    #pragma unroll
    for (int e = 0; e < EMB; ++e) a += zv[e] * w0[e*ORDER + o];
    h1[o] = sinf(freq[o] * a);
  }
  float h2[ORDER];
  #pragma unroll 2
  for (int o = 0; o < ORDER; ++o){
    float a = b1[o];
    #pragma unroll
    for (int p = 0; p < ORDER; ++p) a += h1[p] * w1[p*ORDER + o];
    h2[o] = sinf(freq[o] * a);
  }
  #pragma unroll 2
  for (int o = 0; o < ORDER; ++o){
    float a = b2[o];
    #pragma unroll
    for (int p = 0; p < ORDER; ++p) a += h2[p] * w2[p*ORDER + o];
    ws[WS_H + (size_t)l*ORDER + o] = sinf(freq[o] * a);
  }
}

// ---------------- k[w,l] = (h[l,:]·wf[:,w]) * exp(-t_l*|delta_w|) ----------------
#define WCHUNK 128
__global__ void kgemm_kernel(const float* __restrict__ wf, const float* __restrict__ deltas,
                             float* __restrict__ ws){
  int l = (blockIdx.x & 31) * 256 + threadIdx.x;
  int wbase = (blockIdx.x >> 5) * WCHUNK;
  float hv[ORDER];
  #pragma unroll
  for (int o = 0; o < ORDER; ++o) hv[o] = ws[WS_H + (size_t)l*ORDER + o];
  float tl = (float)l * (1.0f / 8191.0f);
  #pragma unroll 1
  for (int wi = 0; wi < WCHUNK; ++wi){
    int w = wbase + wi;
    float a = 0.f;
    #pragma unroll
    for (int o = 0; o < ORDER; ++o) a += hv[o] * wf[o*WSEQ + w];
    float mod = expf(-tl * fabsf(deltas[w]));
    ws[WS_KF + (size_t)w*KFROW + l] = a * mod;
  }
}

// ---------------- Stockham radix-4 pass (in-place, register-staged) ----------------
__device__ __forceinline__ void pass_r4(float2* sC,
        const float2* __restrict__ twN, int tid, int l2, float sgn){
  int ns = 1 << l2;
  int sh = 11 - l2;
  float2 o[8][4];
  int bas[8];
  #pragma unroll
  for (int i = 0; i < 8; ++i){
    int j = tid + (i << 8);
    int u = j & (ns - 1);
    float2 t = twN[u << sh];
    float w1r = t.x,               w1i = sgn * t.y;
    float w2r = w1r*w1r - w1i*w1i, w2i = 2.f*w1r*w1i;
    float w3r = w2r*w1r - w2i*w1i, w3i = w2r*w1i + w2i*w1r;
    float2 v0 = sC[swz(j)];
    float2 a1 = sC[swz(j+2048)];
    float2 a2 = sC[swz(j+4096)];
    float2 a3 = sC[swz(j+6144)];
    float v1r = a1.x*w1r - a1.y*w1i, v1i = a1.x*w1i + a1.y*w1r;
    float v2r = a2.x*w2r - a2.y*w2i, v2i = a2.x*w2i + a2.y*w2r;
    float v3r = a3.x*w3r - a3.y*w3i, v3i = a3.x*w3i + a3.y*w3r;
    float t0r = v0.x+v2r, t0i = v0.y+v2i;
    float t1r = v0.x-v2r, t1i = v0.y-v2i;
    float t2r = v1r+v3r, t2i = v1i+v3i;
    float t3r = v1r-v3r, t3i = v1i-v3i;
    o[i][0] = make_float2(t0r+t2r,       t0i+t2i);
    o[i][2] = make_float2(t0r-t2r,       t0i-t2i);
    o[i][1] = make_float2(t1r + sgn*t3i, t1i - sgn*t3r);
    o[i][3] = make_float2(t1r - sgn*t3i, t1i + sgn*t3r);
    bas[i] = ((j >> l2) << (l2 + 2)) + u;
  }
  __syncthreads();
  #pragma unroll
  for (int i = 0; i < 8; ++i){
    #pragma unroll
    for (int r = 0; r < 4; ++r){
      sC[swz(bas[i] + (r << l2))] = o[i][r];
    }
  }
  __syncthreads();
}

__device__ __forceinline__ void fft_passes(float2* sC,
        const float2* __restrict__ twN, int tid, float sgn){
  #pragma unroll 1
  for (int p = 0; p < 6; ++p)
    pass_r4(sC, twN, tid, 1 + 2*p, sgn);
}

// full radix-2 first pass for the inverse (Ns=1, no twiddle)
__device__ __forceinline__ void pass_r2_first(float2* sC, int tid){
  float4 v[16];
  #pragma unroll
  for (int i = 0; i < 16; ++i){
    int j = tid + (i << 8);
    float2 a = sC[swz(j)];
    float2 b = sC[swz(j+4096)];
    v[i] = make_float4(a.x+b.x, a.y+b.y, a.x-b.x, a.y-b.y);
  }
  __syncthreads();
  #pragma unroll
  for (int i = 0; i < 16; ++i){
    int j = tid + (i << 8);
    ((float4*)sC)[swz(2*j) >> 1] = v[i];   // covers swz(2j), swz(2j)+1 == swz(2j+1)
  }
  __syncthreads();
}

// unpack packed-complex FFT C -> real spectrum pair U[t], U[N-t]
__device__ __forceinline__ void unpack_item(int t, const float2* sC,
        const float2* __restrict__ tw2N,
        float& Ukr, float& Uki, float& Unr, float& Uni){
  int tn = (NFFT - t) & (NFFT - 1);
  float2 a = sC[swz(t)];
  float2 b = sC[swz(tn)];
  float Er = 0.5f*(a.x+b.x), Ei = 0.5f*(a.y-b.y);
  float Pr = 0.5f*(a.x-b.x), Pi = 0.5f*(a.y+b.y);
  float Or = Pi, Oi = -Pr;                       // O = -i*P
  float2 tw = tw2N[t];                           // e^{-i pi t / N}
  float Qr = Or*tw.x - Oi*tw.y, Qi = Or*tw.y + Oi*tw.x;
  Ukr = Er + Qr; Uki = Ei + Qi;                  // U[t]   = E + Q
  Unr = Er - Qr; Uni = Qi - Ei;                  // U[N-t] = conj(E - Q)
}

// ---------------- per-w filter spectrum: K = rfft(k,16384)/16384 ----------------
__global__ void __launch_bounds__(256, 2)
fftk_kernel(float* __restrict__ ws){
  __shared__ float2 sC[NFFT];
  const int tid = threadIdx.x;
  const int w = blockIdx.x;
  float* kfr = ws + WS_KF + (size_t)w * KFROW;
  const float2* twN  = (const float2*)(ws + WS_TWN);
  const float2* tw2N = (const float2*)(ws + WS_TW2N);
  #pragma unroll
  for (int q = 0; q < 16; ++q){                  // pack + trivial first radix-2 (zero pad)
    int j = tid + (q << 8);
    float2 v = ((const float2*)kfr)[j];
    ((float4*)sC)[swz(2*j) >> 1] = make_float4(v.x, v.y, v.x, v.y);
  }
  __syncthreads();
  fft_passes(sC, twN, tid, 1.0f);
  const float sc = 1.0f / 16384.0f;
  #pragma unroll
  for (int i = 0; i < 16; ++i){
    int t = tid + (i << 8);
    float Ukr, Uki, Unr, Uni;
    unpack_item(t, sC, tw2N, Ukr, Uki, Unr, Uni);
    ((float2*)kfr)[t]        = make_float2(Ukr*sc, Uki*sc);
    ((float2*)kfr)[NFFT - t] = make_float2(Unr*sc, Uni*sc);
  }
  if (tid == 0){
    float Ukr, Uki, Unr, Uni;
    unpack_item(MH, sC, tw2N, Ukr, Uki, Unr, Uni);
    ((float2*)kfr)[MH] = make_float2(Ukr*sc, Uki*sc);
  }
}

// fused unpack -> multiply by K -> repack for inverse
__device__ __forceinline__ void pair_item(int t, const float2* sC,
        const float* __restrict__ kfr, const float2* __restrict__ tw2N,
        float& Dtr, float& Dti, float& Dnr, float& Dni){
  float Ukr, Uki, Unr, Uni;
  unpack_item(t, sC, tw2N, Ukr, Uki, Unr, Uni);
  float2 tw = tw2N[t];
  float2 Kk = ((const float2*)kfr)[t];
  float2 Kn = ((const float2*)kfr)[NFFT - t];
  float Ykr = Ukr*Kk.x - Uki*Kk.y, Yki = Ukr*Kk.y + Uki*Kk.x;
  float Ynr = Unr*Kn.x - Uni*Kn.y, Yni = Unr*Kn.y + Uni*Kn.x;
  float Ar = Ykr + Ynr, Ai = Yki - Yni;          // A = Yk + conj(Yn)
  float Br = Ykr - Ynr, Bi = Yki + Yni;          // B = Yk - conj(Yn)
  float Rr = Br*tw.x + Bi*tw.y;                  // R = conj(tw) * B
  float Ri = Bi*tw.x - Br*tw.y;
  Dtr = Ar - Ri; Dti = Ai + Rr;                  // D[t]   = A + iR
  Dnr = Ar + Ri; Dni = Rr - Ai;                  // D[N-t] = conj(A - iR)
}

// ---------------- main: per (b,w) row FFT convolution ----------------
__global__ void __launch_bounds__(256, 2)
conv_kernel(const float* __restrict__ x, const float* __restrict__ ws,
            const float* __restrict__ Dw, float* __restrict__ out){
  __shared__ float2 sC[NFFT];
  const int tid = threadIdx.x;
  // XCD-aware swizzle: each XCD gets a contiguous chunk of logical ids so the
  // 4 blocks sharing one K row co-reside on one XCD's L2. 3072 = 8 * 384.
  const int blk = (blockIdx.x & 7) * 384 + (blockIdx.x >> 3);
  const int b = blk & 3, w = blk >> 2;           // consecutive logical blocks share K row
  const float2* twN  = (const float2*)(ws + WS_TWN);
  const float2* tw2N = (const float2*)(ws + WS_TW2N);
  const float* kfr = ws + WS_KF + (size_t)w * KFROW;
  const size_t rowoff = ((size_t)(b*WSEQ + w)) * LSEQ;
  const float2* xrow = (const float2*)(x + rowoff);
  float2 xr[16];
  #pragma unroll
  for (int q = 0; q < 16; ++q){                  // load row, pack, trivial first pass
    int j = tid + (q << 8);
    float2 v = xrow[j];
    xr[q] = v;
    ((float4*)sC)[swz(2*j) >> 1] = make_float4(v.x, v.y, v.x, v.y);
  }
  __syncthreads();
  fft_passes(sC, twN, tid, 1.0f);                // forward
  // pair phase (register staged: read all C, then write all D)
  float2 Dt[16], Dn[16];
  float etr = 0.f, eti = 0.f;
  #pragma unroll
  for (int i = 0; i < 16; ++i){
    int t = tid + (i << 8);
    float a, bq, c, d;
    pair_item(t, sC, kfr, tw2N, a, bq, c, d);
    Dt[i] = make_float2(a, bq); Dn[i] = make_float2(c, d);
  }
  if (tid == 0){
    float a, bq, c, d;
    pair_item(MH, sC, kfr, tw2N, a, bq, c, d);
    etr = a; eti = bq;
  }
  __syncthreads();
  #pragma unroll
  for (int i = 0; i < 16; ++i){
    int t = tid + (i << 8);
    int tn = (NFFT - t) & (NFFT - 1);
    sC[swz(t)]  = Dt[i];
    sC[swz(tn)] = Dn[i];
  }
  if (tid == 0){ sC[swz(MH)] = make_float2(etr, eti); }
  __syncthreads();
  // inverse: radix-2 full pass + 6 conjugate radix-4 passes
  pass_r2_first(sC, tid);
  fft_passes(sC, twN, tid, -1.0f);
  // epilogue: y[2j],y[2j+1] = Re/Im d[j]; add residual x*D[w]
  const float dsc = Dw[w];
  float2* orow = (float2*)(out + rowoff);
  #pragma unroll
  for (int q = 0; q < 16; ++q){
    int j = tid + (q << 8);
    float2 dv = sC[swz(j)];
    float2 o;
    o.x = dv.x + xr[q].x * dsc;
    o.y = dv.y + xr[q].y * dsc;
    orow[j] = o;
  }
}

extern "C" void kernel_launch(void* const* d_in, const int* in_sizes, int n_in,
                              void* d_out, int out_size, void* d_ws, size_t ws_size,
                              hipStream_t stream){
  const float* x      = (const float*)d_in[0];
  const float* z      = (const float*)d_in[1];
  const float* freq   = (const float*)d_in[2];
  const float* w0     = (const float*)d_in[3];
  const float* b0     = (const float*)d_in[4];
  const float* w1     = (const float*)d_in[5];
  const float* b1     = (const float*)d_in[6];
  const float* w2     = (const float*)d_in[7];
  const float* b2     = (const float*)d_in[8];
  const float* wf     = (const float*)d_in[9];
  const float* deltas = (const float*)d_in[10];
  const float* Dw     = (const float*)d_in[11];
  float* ws  = (float*)d_ws;
  float* out = (float*)d_out;

  tables_kernel<<<dim3(40),  dim3(256), 0, stream>>>(ws);
  mlp_kernel   <<<dim3(32),  dim3(256), 0, stream>>>(z, freq, w0, b0, w1, b1, w2, b2, ws);
  kgemm_kernel <<<dim3(192), dim3(256), 0, stream>>>(wf, deltas, ws);
  fftk_kernel  <<<dim3(WSEQ), dim3(256), 0, stream>>>(ws);
  conv_kernel  <<<dim3(BSZ*WSEQ), dim3(256), 0, stream>>>(x, ws, Dw, out);
}

// Round 4
// 557.764 us; speedup vs baseline: 1.5372x; 1.5372x over previous
//
#include <hip/hip_runtime.h>

#define BSZ   4
#define WSEQ  768
#define LSEQ  8192
#define NFFT  8192   // packed complex FFT length (real length 16384)
#define MH    4096
#define EMB   33
#define ORDER 64

// workspace layout (float units)
#define KFROW   16448          // per-w row: holds k reals then 8193 complex (padded)
#define WS_TWN  0              // 2048 complex  e^{-2pi q/8192}
#define WS_TW2N 4096           // 8192 complex  e^{-2pi k/16384}
#define WS_H    20480          // h_T: [64][8192] (o-major)
#define WS_KF   544768         // 768 rows x KFROW floats  (~50 MB total ws)

__device__ __forceinline__ int swz(int a){ return a ^ (((a >> 5) & 7) << 2); }

// ---------------- twiddle tables (built in fp64 once per launch) ----------------
__global__ void tables_kernel(float* __restrict__ ws){
  int t = blockIdx.x * 256 + threadIdx.x;
  const double TWO_PI = 6.283185307179586476925286766559;
  if (t < 2048){
    double ang = -TWO_PI * (double)t / 8192.0;
    ws[WS_TWN + 2*t]   = (float)cos(ang);
    ws[WS_TWN + 2*t+1] = (float)sin(ang);
  }
  int k = t - 2048;
  if (k >= 0 && k < NFFT){
    double ang = -TWO_PI * (double)k / 16384.0;
    ws[WS_TW2N + 2*k]   = (float)cos(ang);
    ws[WS_TW2N + 2*k+1] = (float)sin(ang);
  }
}

// ---------------- implicit filter MLP: z[8192,33] -> h_T[64][8192] ----------------
__global__ void mlp_kernel(const float* __restrict__ z, const float* __restrict__ freq,
                           const float* __restrict__ w0, const float* __restrict__ b0,
                           const float* __restrict__ w1, const float* __restrict__ b1,
                           const float* __restrict__ w2, const float* __restrict__ b2,
                           float* __restrict__ ws){
  int l = blockIdx.x * 256 + threadIdx.x;
  if (l >= LSEQ) return;
  float zv[EMB];
  #pragma unroll
  for (int e = 0; e < EMB; ++e) zv[e] = z[l*EMB + e];
  float h1[ORDER];
  #pragma unroll 2
  for (int o = 0; o < ORDER; ++o){
    float a = b0[o];
    #pragma unroll
    for (int e = 0; e < EMB; ++e) a += zv[e] * w0[e*ORDER + o];
    h1[o] = sinf(freq[o] * a);
  }
  float h2[ORDER];
  #pragma unroll 2
  for (int o = 0; o < ORDER; ++o){
    float a = b1[o];
    #pragma unroll
    for (int p = 0; p < ORDER; ++p) a += h1[p] * w1[p*ORDER + o];
    h2[o] = sinf(freq[o] * a);
  }
  #pragma unroll 2
  for (int o = 0; o < ORDER; ++o){
    float a = b2[o];
    #pragma unroll
    for (int p = 0; p < ORDER; ++p) a += h2[p] * w2[p*ORDER + o];
    ws[WS_H + o*LSEQ + l] = sinf(freq[o] * a);   // transposed, coalesced per o
  }
}

// ---------------- kgemm: k[w,l] = (h_T[:,l]·wf[:,w]) * exp(-t_l*|delta_w|) ----------------
// Tiled GEMM: M=8192(l) x N=768(w) x K=64(o). Tile 128x128, 8x8 micro-tile.
__global__ void __launch_bounds__(256, 2)
kgemm_kernel(const float* __restrict__ wf, const float* __restrict__ deltas,
             float* __restrict__ ws){
  __shared__ float As[64][128];   // [o][l] 32 KB
  __shared__ float Bs[64][128];   // [o][w] 32 KB
  const int tid = threadIdx.x;
  const int lb = (blockIdx.x & 63) << 7;        // 64 l-blocks * 128
  const int wb = (blockIdx.x >> 6) << 7;        // 6 w-blocks * 128
  // stage A (h_T rows) and B (wf rows): both [64][128] coalesced float4 copies
  #pragma unroll
  for (int q = 0; q < 8; ++q){
    int idx = q*256 + tid;          // float4 index in [0,2048)
    int o = idx >> 5;
    int c = (idx & 31) << 2;
    *(float4*)&As[o][c] = *(const float4*)&ws[WS_H + o*LSEQ + lb + c];
    *(float4*)&Bs[o][c] = *(const float4*)&wf[o*WSEQ + wb + c];
  }
  __syncthreads();
  const int tx = tid & 15;          // w dimension: w = wb + tx + j*16
  const int ty = tid >> 4;          // l dimension: l = lb + ty*8 + i
  float acc[8][8];
  #pragma unroll
  for (int i = 0; i < 8; ++i)
    #pragma unroll
    for (int j = 0; j < 8; ++j) acc[i][j] = 0.f;
  #pragma unroll 4
  for (int ko = 0; ko < 64; ++ko){
    float a[8], b[8];
    #pragma unroll
    for (int i = 0; i < 8; ++i) a[i] = As[ko][ty*8 + i];    // 2x ds_read_b128, broadcast
    #pragma unroll
    for (int j = 0; j < 8; ++j) b[j] = Bs[ko][tx + j*16];   // 8x b32, 16 consecutive banks
    #pragma unroll
    for (int i = 0; i < 8; ++i)
      #pragma unroll
      for (int j = 0; j < 8; ++j) acc[i][j] += a[i]*b[j];
  }
  // epilogue: modulate + store float4 along l
  const float ool = 1.0f / 8191.0f;
  #pragma unroll
  for (int j = 0; j < 8; ++j){
    int w = wb + tx + j*16;
    float ad = fabsf(deltas[w]);
    float e[8];
    #pragma unroll
    for (int i = 0; i < 8; ++i){
      float tl = (float)(lb + ty*8 + i) * ool;
      e[i] = acc[i][j] * __expf(-tl * ad);
    }
    float* dst = ws + WS_KF + (size_t)w*KFROW + lb + ty*8;
    *(float4*)dst       = make_float4(e[0], e[1], e[2], e[3]);
    *(float4*)(dst + 4) = make_float4(e[4], e[5], e[6], e[7]);
  }
}

// ---------------- Stockham radix-4 pass (in-place, register-staged) ----------------
__device__ __forceinline__ void pass_r4(float2* sC,
        const float2* __restrict__ twN, int tid, int l2, float sgn){
  int ns = 1 << l2;
  int sh = 11 - l2;
  float2 o[8][4];
  int bas[8];
  #pragma unroll
  for (int i = 0; i < 8; ++i){
    int j = tid + (i << 8);
    int u = j & (ns - 1);
    float2 t = twN[u << sh];
    float w1r = t.x,               w1i = sgn * t.y;
    float w2r = w1r*w1r - w1i*w1i, w2i = 2.f*w1r*w1i;
    float w3r = w2r*w1r - w2i*w1i, w3i = w2r*w1i + w2i*w1r;
    float2 v0 = sC[swz(j)];
    float2 a1 = sC[swz(j+2048)];
    float2 a2 = sC[swz(j+4096)];
    float2 a3 = sC[swz(j+6144)];
    float v1r = a1.x*w1r - a1.y*w1i, v1i = a1.x*w1i + a1.y*w1r;
    float v2r = a2.x*w2r - a2.y*w2i, v2i = a2.x*w2i + a2.y*w2r;
    float v3r = a3.x*w3r - a3.y*w3i, v3i = a3.x*w3i + a3.y*w3r;
    float t0r = v0.x+v2r, t0i = v0.y+v2i;
    float t1r = v0.x-v2r, t1i = v0.y-v2i;
    float t2r = v1r+v3r, t2i = v1i+v3i;
    float t3r = v1r-v3r, t3i = v1i-v3i;
    o[i][0] = make_float2(t0r+t2r,       t0i+t2i);
    o[i][2] = make_float2(t0r-t2r,       t0i-t2i);
    o[i][1] = make_float2(t1r + sgn*t3i, t1i - sgn*t3r);
    o[i][3] = make_float2(t1r - sgn*t3i, t1i + sgn*t3r);
    bas[i] = ((j >> l2) << (l2 + 2)) + u;
  }
  __syncthreads();
  #pragma unroll
  for (int i = 0; i < 8; ++i){
    #pragma unroll
    for (int r = 0; r < 4; ++r){
      sC[swz(bas[i] + (r << l2))] = o[i][r];
    }
  }
  __syncthreads();
}

__device__ __forceinline__ void fft_passes(float2* sC,
        const float2* __restrict__ twN, int tid, float sgn){
  #pragma unroll 1
  for (int p = 0; p < 6; ++p)
    pass_r4(sC, twN, tid, 1 + 2*p, sgn);
}

// full radix-2 first pass for the inverse (Ns=1, no twiddle)
__device__ __forceinline__ void pass_r2_first(float2* sC, int tid){
  float4 v[16];
  #pragma unroll
  for (int i = 0; i < 16; ++i){
    int j = tid + (i << 8);
    float2 a = sC[swz(j)];
    float2 b = sC[swz(j+4096)];
    v[i] = make_float4(a.x+b.x, a.y+b.y, a.x-b.x, a.y-b.y);
  }
  __syncthreads();
  #pragma unroll
  for (int i = 0; i < 16; ++i){
    int j = tid + (i << 8);
    ((float4*)sC)[swz(2*j) >> 1] = v[i];   // covers swz(2j), swz(2j)+1 == swz(2j+1)
  }
  __syncthreads();
}

// unpack packed-complex FFT C -> real spectrum pair U[t], U[N-t]
__device__ __forceinline__ void unpack_item(int t, const float2* sC,
        const float2* __restrict__ tw2N,
        float& Ukr, float& Uki, float& Unr, float& Uni){
  int tn = (NFFT - t) & (NFFT - 1);
  float2 a = sC[swz(t)];
  float2 b = sC[swz(tn)];
  float Er = 0.5f*(a.x+b.x), Ei = 0.5f*(a.y-b.y);
  float Pr = 0.5f*(a.x-b.x), Pi = 0.5f*(a.y+b.y);
  float Or = Pi, Oi = -Pr;                       // O = -i*P
  float2 tw = tw2N[t];                           // e^{-i pi t / N}
  float Qr = Or*tw.x - Oi*tw.y, Qi = Or*tw.y + Oi*tw.x;
  Ukr = Er + Qr; Uki = Ei + Qi;                  // U[t]   = E + Q
  Unr = Er - Qr; Uni = Qi - Ei;                  // U[N-t] = conj(E - Q)
}

// ---------------- per-w filter spectrum: K = rfft(k,16384)/16384 ----------------
__global__ void __launch_bounds__(256, 2)
fftk_kernel(float* __restrict__ ws){
  __shared__ float2 sC[NFFT];
  const int tid = threadIdx.x;
  const int w = blockIdx.x;
  float* kfr = ws + WS_KF + (size_t)w * KFROW;
  const float2* twN  = (const float2*)(ws + WS_TWN);
  const float2* tw2N = (const float2*)(ws + WS_TW2N);
  #pragma unroll
  for (int q = 0; q < 16; ++q){                  // pack + trivial first radix-2 (zero pad)
    int j = tid + (q << 8);
    float2 v = ((const float2*)kfr)[j];
    ((float4*)sC)[swz(2*j) >> 1] = make_float4(v.x, v.y, v.x, v.y);
  }
  __syncthreads();
  fft_passes(sC, twN, tid, 1.0f);
  const float sc = 1.0f / 16384.0f;
  #pragma unroll
  for (int i = 0; i < 16; ++i){
    int t = tid + (i << 8);
    float Ukr, Uki, Unr, Uni;
    unpack_item(t, sC, tw2N, Ukr, Uki, Unr, Uni);
    ((float2*)kfr)[t]        = make_float2(Ukr*sc, Uki*sc);
    ((float2*)kfr)[NFFT - t] = make_float2(Unr*sc, Uni*sc);
  }
  if (tid == 0){
    float Ukr, Uki, Unr, Uni;
    unpack_item(MH, sC, tw2N, Ukr, Uki, Unr, Uni);
    ((float2*)kfr)[MH] = make_float2(Ukr*sc, Uki*sc);
  }
}

// fused unpack -> multiply by K -> repack for inverse
__device__ __forceinline__ void pair_item(int t, const float2* sC,
        const float* __restrict__ kfr, const float2* __restrict__ tw2N,
        float& Dtr, float& Dti, float& Dnr, float& Dni){
  float Ukr, Uki, Unr, Uni;
  unpack_item(t, sC, tw2N, Ukr, Uki, Unr, Uni);
  float2 tw = tw2N[t];
  float2 Kk = ((const float2*)kfr)[t];
  float2 Kn = ((const float2*)kfr)[NFFT - t];
  float Ykr = Ukr*Kk.x - Uki*Kk.y, Yki = Ukr*Kk.y + Uki*Kk.x;
  float Ynr = Unr*Kn.x - Uni*Kn.y, Yni = Unr*Kn.y + Uni*Kn.x;
  float Ar = Ykr + Ynr, Ai = Yki - Yni;          // A = Yk + conj(Yn)
  float Br = Ykr - Ynr, Bi = Yki + Yni;          // B = Yk - conj(Yn)
  float Rr = Br*tw.x + Bi*tw.y;                  // R = conj(tw) * B
  float Ri = Bi*tw.x - Br*tw.y;
  Dtr = Ar - Ri; Dti = Ai + Rr;                  // D[t]   = A + iR
  Dnr = Ar + Ri; Dni = Rr - Ai;                  // D[N-t] = conj(A - iR)
}

// ---------------- main: per (b,w) row FFT convolution ----------------
__global__ void __launch_bounds__(256, 2)
conv_kernel(const float* __restrict__ x, const float* __restrict__ ws,
            const float* __restrict__ Dw, float* __restrict__ out){
  __shared__ float2 sC[NFFT];
  const int tid = threadIdx.x;
  // XCD-aware swizzle: each XCD gets a contiguous chunk of logical ids so the
  // 4 blocks sharing one K row co-reside on one XCD's L2. 3072 = 8 * 384.
  const int blk = (blockIdx.x & 7) * 384 + (blockIdx.x >> 3);
  const int b = blk & 3, w = blk >> 2;           // consecutive logical blocks share K row
  const float2* twN  = (const float2*)(ws + WS_TWN);
  const float2* tw2N = (const float2*)(ws + WS_TW2N);
  const float* kfr = ws + WS_KF + (size_t)w * KFROW;
  const size_t rowoff = ((size_t)(b*WSEQ + w)) * LSEQ;
  const float2* xrow = (const float2*)(x + rowoff);
  float2 xr[16];
  #pragma unroll
  for (int q = 0; q < 16; ++q){                  // load row, pack, trivial first pass
    int j = tid + (q << 8);
    float2 v = xrow[j];
    xr[q] = v;
    ((float4*)sC)[swz(2*j) >> 1] = make_float4(v.x, v.y, v.x, v.y);
  }
  __syncthreads();
  fft_passes(sC, twN, tid, 1.0f);                // forward
  // pair phase (register staged: read all C, then write all D)
  float2 Dt[16], Dn[16];
  float etr = 0.f, eti = 0.f;
  #pragma unroll
  for (int i = 0; i < 16; ++i){
    int t = tid + (i << 8);
    float a, bq, c, d;
    pair_item(t, sC, kfr, tw2N, a, bq, c, d);
    Dt[i] = make_float2(a, bq); Dn[i] = make_float2(c, d);
  }
  if (tid == 0){
    float a, bq, c, d;
    pair_item(MH, sC, kfr, tw2N, a, bq, c, d);
    etr = a; eti = bq;
  }
  __syncthreads();
  #pragma unroll
  for (int i = 0; i < 16; ++i){
    int t = tid + (i << 8);
    int tn = (NFFT - t) & (NFFT - 1);
    sC[swz(t)]  = Dt[i];
    sC[swz(tn)] = Dn[i];
  }
  if (tid == 0){ sC[swz(MH)] = make_float2(etr, eti); }
  __syncthreads();
  // inverse: radix-2 full pass + 6 conjugate radix-4 passes
  pass_r2_first(sC, tid);
  fft_passes(sC, twN, tid, -1.0f);
  // epilogue: y[2j],y[2j+1] = Re/Im d[j]; add residual x*D[w]
  const float dsc = Dw[w];
  float2* orow = (float2*)(out + rowoff);
  #pragma unroll
  for (int q = 0; q < 16; ++q){
    int j = tid + (q << 8);
    float2 dv = sC[swz(j)];
    float2 o;
    o.x = dv.x + xr[q].x * dsc;
    o.y = dv.y + xr[q].y * dsc;
    orow[j] = o;
  }
}

extern "C" void kernel_launch(void* const* d_in, const int* in_sizes, int n_in,
                              void* d_out, int out_size, void* d_ws, size_t ws_size,
                              hipStream_t stream){
  const float* x      = (const float*)d_in[0];
  const float* z      = (const float*)d_in[1];
  const float* freq   = (const float*)d_in[2];
  const float* w0     = (const float*)d_in[3];
  const float* b0     = (const float*)d_in[4];
  const float* w1     = (const float*)d_in[5];
  const float* b1     = (const float*)d_in[6];
  const float* w2     = (const float*)d_in[7];
  const float* b2     = (const float*)d_in[8];
  const float* wf     = (const float*)d_in[9];
  const float* deltas = (const float*)d_in[10];
  const float* Dw     = (const float*)d_in[11];
  float* ws  = (float*)d_ws;
  float* out = (float*)d_out;

  tables_kernel<<<dim3(40),  dim3(256), 0, stream>>>(ws);
  mlp_kernel   <<<dim3(32),  dim3(256), 0, stream>>>(z, freq, w0, b0, w1, b1, w2, b2, ws);
  kgemm_kernel <<<dim3(384), dim3(256), 0, stream>>>(wf, deltas, ws);
  fftk_kernel  <<<dim3(WSEQ), dim3(256), 0, stream>>>(ws);
  conv_kernel  <<<dim3(BSZ*WSEQ), dim3(256), 0, stream>>>(x, ws, Dw, out);
}